// Round 1
// baseline (143.778 us; speedup 1.0000x reference)
//
#include <hip/hip_runtime.h>

#define N_PSF 32
#define BC    32
#define Hh    256
#define Ww    256
#define Dd    64          // coarse spatial dim (256/4)
#define BWk   31          // band width
#define PADk  15
#define PX    16          // pixels per block
#define XW    (PX + BWk - 1)      // 46 staged x positions
#define XSTR  36                   // xp LDS stride (bank spread + 16B align)
#define WSTR_K 36                  // w LDS k-stride
#define WSTR_X (16 * WSTR_K + 4)   // 580: xi-stride, ≡4 mod 32 for bank spread
#define KH0   16                   // first k-half size
#define NTH   256

__global__ __launch_bounds__(NTH, 3)
void band_kernel(const float* __restrict__ pw,
                 const float* __restrict__ x,
                 float* __restrict__ out)
{
    __shared__ __align__(16) float smem[PX * WSTR_X + XW * XSTR];
    float* w_lds  = smem;                 // [xi][kk][n] strides WSTR_X / WSTR_K
    float* xp_lds = smem + PX * WSTR_X;   // [xw][bc]   stride XSTR

    const int tid = threadIdx.x;
    const int bx  = blockIdx.x;           // x-tile index
    const int y   = blockIdx.y;
    const int x0  = bx * PX;

    const int xi = tid & 15;              // pixel within tile
    const int ng = (tid >> 4) & 3;        // n-group (8 n each)
    const int bg = tid >> 6;              // bc-group (8 bc each) == wave id

    // --- y interpolation (block-uniform), exact scale-4 half-pixel mapping ---
    const float FR[4] = {0.625f, 0.875f, 0.125f, 0.375f};
    const int yq = y >> 2, ry = y & 3;
    const int y0i = yq + ((ry < 2) ? -1 : 0);
    const float fy = FR[ry];
    const int y0c = (y0i < 0) ? 0 : y0i;
    const int y1c = (y0i + 1 > Dd - 1) ? Dd - 1 : y0i + 1;

    // --- stage x rows (zero-padded) into LDS: xp[xw][bc] ---
    for (int i = tid; i < XW * BC; i += NTH) {
        int xw = i % XW;                  // contiguous gx for consecutive lanes
        int bc = i / XW;
        int gx = x0 - PADk + xw;
        float v = 0.f;
        if (gx >= 0 && gx < Ww) v = x[(bc * Hh + y) * Ww + gx];
        xp_lds[xw * XSTR + bc] = v;
    }

    // --- per-thread staging pairs: p = tid, tid+256 -> (xi_s = p&15, n = p>>4) ---
    const float* rbase[2][4];
    float cc[2][4];
    #pragma unroll
    for (int pp = 0; pp < 2; ++pp) {
        int p  = tid + pp * NTH;
        int xs = p & 15;
        int n  = p >> 4;                  // 0..31
        int xg = x0 + xs;
        int xq = xg >> 2, rx = xg & 3;
        int x0i = xq + ((rx < 2) ? -1 : 0);
        float fx = FR[rx];
        int x0c = (x0i < 0) ? 0 : x0i;
        int x1c = (x0i + 1 > Dd - 1) ? Dd - 1 : x0i + 1;
        rbase[pp][0] = pw + ((size_t)n * 4096 + (size_t)y0c * Dd + x0c) * BWk;
        rbase[pp][1] = pw + ((size_t)n * 4096 + (size_t)y0c * Dd + x1c) * BWk;
        rbase[pp][2] = pw + ((size_t)n * 4096 + (size_t)y1c * Dd + x0c) * BWk;
        rbase[pp][3] = pw + ((size_t)n * 4096 + (size_t)y1c * Dd + x1c) * BWk;
        cc[pp][0] = (1.f - fy) * (1.f - fx);
        cc[pp][1] = (1.f - fy) * fx;
        cc[pp][2] = fy * (1.f - fx);
        cc[pp][3] = fy * fx;
    }

    float acc[8][8];
    #pragma unroll
    for (int i = 0; i < 8; ++i)
        #pragma unroll
        for (int j = 0; j < 8; ++j) acc[i][j] = 0.f;

    #pragma unroll
    for (int h = 0; h < 2; ++h) {
        const int k0 = h * KH0;
        const int kn = (h == 0) ? KH0 : (BWk - KH0);   // 16 then 15

        // --- stage interpolated weights for this k-half: w[xi][kk][n] ---
        #pragma unroll
        for (int pp = 0; pp < 2; ++pp) {
            int p  = tid + pp * NTH;
            int xs = p & 15;
            int n  = p >> 4;
            float* dst = w_lds + xs * WSTR_X + n;
            const float* b0 = rbase[pp][0];
            const float* b1 = rbase[pp][1];
            const float* b2 = rbase[pp][2];
            const float* b3 = rbase[pp][3];
            #pragma unroll 4
            for (int kk = 0; kk < kn; ++kk) {
                int k = k0 + kk;
                float v = cc[pp][0] * b0[k] + cc[pp][1] * b1[k]
                        + cc[pp][2] * b2[k] + cc[pp][3] * b3[k];
                dst[kk * WSTR_K] = v;
            }
        }
        __syncthreads();

        // --- main MAC loop for this k-half ---
        #pragma unroll 4
        for (int kk = 0; kk < kn; ++kk) {
            int k = k0 + kk;
            float xr[8], wr[8];
            const int xoff = (xi + k) * XSTR + bg * 8;
            const int woff = xi * WSTR_X + kk * WSTR_K + ng * 8;
            *(float4*)&xr[0] = *(const float4*)&xp_lds[xoff];
            *(float4*)&xr[4] = *(const float4*)&xp_lds[xoff + 4];
            *(float4*)&wr[0] = *(const float4*)&w_lds[woff];
            *(float4*)&wr[4] = *(const float4*)&w_lds[woff + 4];
            #pragma unroll
            for (int bi = 0; bi < 8; ++bi)
                #pragma unroll
                for (int nj = 0; nj < 8; ++nj)
                    acc[bi][nj] = fmaf(xr[bi], wr[nj], acc[bi][nj]);
        }
        __syncthreads();
    }

    // --- epilogue: nontemporal streaming stores, x-contiguous lanes ---
    const int bc0 = bg * 8, n0 = ng * 8;
    const int xg  = x0 + xi;
    float* obase = out + (size_t)(bc0 * N_PSF + n0) * (Hh * Ww) + y * Ww + xg;
    #pragma unroll
    for (int bi = 0; bi < 8; ++bi)
        #pragma unroll
        for (int nj = 0; nj < 8; ++nj)
            __builtin_nontemporal_store(acc[bi][nj],
                obase + (size_t)(bi * N_PSF + nj) * (Hh * Ww));
}

extern "C" void kernel_launch(void* const* d_in, const int* in_sizes, int n_in,
                              void* d_out, int out_size, void* d_ws, size_t ws_size,
                              hipStream_t stream) {
    const float* pw = (const float*)d_in[0];   // pre_weights [32,4096,31]
    const float* x  = (const float*)d_in[1];   // x [4,8,256,256]
    float* out = (float*)d_out;                // [32,32,256,256] f32

    dim3 grid(Ww / PX, Hh, 1);
    dim3 block(NTH, 1, 1);
    band_kernel<<<grid, block, 0, stream>>>(pw, x, out);
}